// Round 11
// baseline (491.874 us; speedup 1.0000x reference)
//
#include <hip/hip_runtime.h>
#include <stdint.h>

typedef unsigned short u16;
typedef __attribute__((ext_vector_type(8))) short bf16x8;
typedef __attribute__((ext_vector_type(4))) float f32x4;

__device__ __forceinline__ u16 f2bf(float f) {
  union { float f; uint32_t u; } v; v.f = f;
  uint32_t u = v.u;
  return (u16)((u + 0x7fffu + ((u >> 16) & 1u)) >> 16);
}

__device__ __forceinline__ void gl_lds16(const void* g, void* l) {
  __builtin_amdgcn_global_load_lds(
      (const __attribute__((address_space(1))) uint32_t*)g,
      (__attribute__((address_space(3))) uint32_t*)l, 16, 0, 0);
}

__constant__ int c_off[9] = {0, 1024, 1808, 2384, 2784, 3040, 3184, 3248, 3264};

// ---------------------------------------------------------------------------
// R11: fully fused prep kernel (prep_misc + build_wc). Block ranges:
//   [0,512)        : x (1024x512 f32) -> Xb bf16
//   [512,768)      : lA (4096x64 f32) -> lAb bf16
//   [768,1584)     : transpose ip_w  -> ip_wt
//   [1584,2096)    : transpose out_w -> out_wt (2048 rows, pad 0)
//   [2096,2160)    : transpose lB    -> lBt
//   [2160,5488)    : conv weight scatter row o = b-2160 (self-zeroing)
// ---------------------------------------------------------------------------
__global__ __launch_bounds__(256)
void prep_all(const float* __restrict__ x, u16* __restrict__ Xb,
              const float* __restrict__ lA, u16* __restrict__ lAb,
              const float* __restrict__ ip_w, u16* __restrict__ ip_wt,
              const float* __restrict__ out_w, u16* __restrict__ out_wt,
              const float* __restrict__ lB, u16* __restrict__ lBt,
              const float* w1, const float* w2, const float* w3, const float* w4,
              const float* w5, const float* w6, const float* w7, const float* w8,
              const float* __restrict__ cb,
              u16* __restrict__ Wct, float* __restrict__ bias_c) {
  __shared__ float tile[64][65];
  int b = blockIdx.x;
  const int t = threadIdx.x;
  if (b < 512) {
    const int i = b * 256 + t;
    const float4 v = ((const float4*)x)[i];
    ((ushort4*)Xb)[i] = make_ushort4(f2bf(v.x), f2bf(v.y), f2bf(v.z), f2bf(v.w));
    return;
  }
  b -= 512;
  if (b < 256) {
    const int i = b * 256 + t;
    const float4 v = ((const float4*)lA)[i];
    ((ushort4*)lAb)[i] = make_ushort4(f2bf(v.x), f2bf(v.y), f2bf(v.z), f2bf(v.w));
    return;
  }
  b -= 256;
  if (b < 1392) {
    const float* src; u16* dst; int R, C, bx, by;
    if (b < 816)        { src = ip_w;  dst = ip_wt;  R = 3264; C = 1024; bx = b % 16; by = b / 16; }
    else if (b < 1328)  { b -= 816;  src = out_w; dst = out_wt; R = 1024; C = 1968; bx = b % 32; by = b / 32; }
    else                { b -= 1328; src = lB;    dst = lBt;    R = 64;   C = 4096; bx = b;      by = 0; }
    const int rb = by << 6, cbs = bx << 6;
    for (int i = 0; i < 16; ++i) {
      const int idx = t + (i << 8);
      const int r = idx >> 6, c = idx & 63;
      float v = 0.f;
      if (cbs + c < C) v = src[(size_t)(rb + r) * C + cbs + c];
      tile[r][c] = v;
    }
    __syncthreads();
    for (int i = 0; i < 16; ++i) {
      const int idx = t + (i << 8);
      const int c = idx >> 6, r = idx & 63;
      dst[(size_t)(cbs + c) * R + rb + r] = f2bf(tile[r][c]);
    }
    return;
  }
  // conv weight scatter
  const int o = b - 1392;
  u16* row = Wct + (size_t)o * 512;
  if (t < 128) *(ushort4*)(row + (t << 2)) = make_ushort4(0, 0, 0, 0);
  if (o >= 3264) {
    if (t == 0) bias_c[o] = 0.f;
    return;
  }
  __syncthreads();
  const float* ws[8] = {w1, w2, w3, w4, w5, w6, w7, w8};
  int kidx = 0;
  while (o >= c_off[kidx + 1]) ++kidx;
  const int ks = kidx + 1;
  const int s  = 8 - kidx;
  const int r  = o - c_off[kidx];
  const int f   = r / (s * s);
  const int rem = r - f * s * s;
  const int oi  = rem / s;
  const int oj  = rem - oi * s;
  const float* w = ws[kidx] + (size_t)f * 8 * ks * ks;
  const int ne = 8 * ks * ks;
  for (int e = t; e < ne; e += 256) {
    const int c  = e / (ks * ks);
    const int er = e - c * ks * ks;
    const int di = er / ks;
    const int dj = er - di * ks;
    row[((oi + di) * 8 + (oj + dj)) * 8 + c] = f2bf(w[(c * ks + di) * ks + dj]);
  }
  if (t == 0) bias_c[o] = cb[kidx * 16 + f];
}

// ---------------------------------------------------------------------------
// W_eff kernel (R8 win, ~18us).
// ---------------------------------------------------------------------------
__global__ __launch_bounds__(256)
void weff2(const float* __restrict__ W, const u16* __restrict__ lBt,
           const u16* __restrict__ lAb, u16* __restrict__ Wt) {
  __shared__ __align__(16) u16 As_[64 * 64];
  __shared__ __align__(16) u16 Bs_[64 * 64];
  __shared__ __align__(16) float Wl[64 * 64];
  __shared__ u16 Ct[64 * 68];
  const int t = threadIdx.x;
  const int w = t >> 6, lane = t & 63;
  const int nb = blockIdx.x << 6, kb = blockIdx.y << 6;
  const int m0 = (w & 1) << 5, n0 = (w >> 1) << 5;
  const int lr = lane & 15, lq = lane >> 4;

  for (int i = 0; i < 2; ++i) {
    const int c   = (w << 7) + (i << 6) + lane;
    const int row = c >> 3;
    const int kg  = (c & 7) ^ (row & 7);
    gl_lds16(lBt + (size_t)(nb + row) * 64 + (kg << 3), (char*)As_ + c * 16);
    gl_lds16(lAb + (size_t)(kb + row) * 64 + (kg << 3), (char*)Bs_ + c * 16);
  }
  for (int i = 0; i < 4; ++i) {
    const int c   = (w << 8) + (i << 6) + lane;
    const int row = c >> 4;
    const int cc  = (c & 15) ^ (row & 15);
    gl_lds16(W + (size_t)(kb + row) * 4096 + nb + (cc << 2), (char*)Wl + c * 16);
  }
  __syncthreads();

  f32x4 acc[2][2] = {};
  for (int kk = 0; kk < 2; ++kk) {
    const int kg = (kk << 2) + lq;
    const int sw = (kg ^ (lr & 7)) << 3;
    bf16x8 af[2], bf[2];
    for (int i = 0; i < 2; ++i)
      af[i] = *(const bf16x8*)&As_[(m0 + (i << 4) + lr) * 64 + sw];
    for (int j = 0; j < 2; ++j)
      bf[j] = *(const bf16x8*)&Bs_[(n0 + (j << 4) + lr) * 64 + sw];
    for (int i = 0; i < 2; ++i)
      for (int j = 0; j < 2; ++j)
        acc[i][j] = __builtin_amdgcn_mfma_f32_16x16x32_bf16(af[i], bf[j], acc[i][j], 0, 0, 0);
  }

  for (int i = 0; i < 2; ++i) {
    for (int j = 0; j < 2; ++j) {
      const int cg  = n0 + (j << 4) + lr;
      const int rg0 = m0 + (i << 4) + (lq << 2);
      const int ch  = (rg0 >> 2) ^ (cg & 15);
      const float4 wv4 = *(const float4*)&Wl[cg * 64 + (ch << 2)];
      const float wv[4] = {wv4.x, wv4.y, wv4.z, wv4.w};
      for (int r = 0; r < 4; ++r)
        Ct[(rg0 + r) * 68 + cg] =
            (wv[r] != 0.f) ? f2bf(wv[r] + 2.0f * acc[i][j][r]) : (u16)0;
    }
  }
  __syncthreads();

  const int row = t >> 2, kp = (t & 3) << 4;
  u16* dst = Wt + (size_t)(nb + row) * 4096 + kb + kp;
  const u16* src = &Ct[row * 68 + kp];
  for (int i = 0; i < 4; ++i)
    *(ushort4*)(dst + (i << 2)) = *(const ushort4*)(src + (i << 2));
}

// ---------------------------------------------------------------------------
// bf16 MFMA GEMM, 64x128 block tile, 4 waves (32x64), BK=64, dbuf LDS,
// XOR-swizzled. The workhorse.
// EPI 1: relu(acc + st_in) -> outf + outb   [recurrent control arm]
// EPI 2: acc + bias -> outf, n < nvalid     [output]
// EPI 3: relu(acc + bias) -> outb only      [conv feat]
// ---------------------------------------------------------------------------
template<int EPI>
__global__ __launch_bounds__(256)
void gemm128(const u16* __restrict__ A, int lda,
             const u16* __restrict__ Bt, int ldb, int K,
             const float* __restrict__ bias,
             const float* __restrict__ st_in, int st_ld,
             float* __restrict__ outf, int outf_ld,
             u16* __restrict__ outb, int outb_ld, int nvalid) {
  __shared__ __align__(16) u16 As[2][64 * 64];
  __shared__ __align__(16) u16 Bs[2][128 * 64];
  const int t = threadIdx.x;
  const int w = t >> 6, lane = t & 63;
  const int mb = blockIdx.y << 6, nb = blockIdx.x << 7;
  const int m0 = (w & 1) << 5, n0 = (w >> 1) << 6;
  const int lr = lane & 15, lq = lane >> 4;

  f32x4 acc[2][4] = {};
  const int nk = K >> 6;

  auto stage = [&](int kt, int buf) {
    const int kb = kt << 6;
    for (int i = 0; i < 2; ++i) {
      const int c   = (w << 7) + (i << 6) + lane;
      const int row = c >> 3;
      const int kg  = (c & 7) ^ (row & 7);
      gl_lds16(A + (size_t)(mb + row) * lda + kb + (kg << 3),
               (char*)As[buf] + c * 16);
    }
    for (int i = 0; i < 4; ++i) {
      const int c   = (w << 8) + (i << 6) + lane;
      const int row = c >> 3;
      const int kg  = (c & 7) ^ (row & 7);
      gl_lds16(Bt + (size_t)(nb + row) * ldb + kb + (kg << 3),
               (char*)Bs[buf] + c * 16);
    }
  };

  stage(0, 0);
  for (int kt = 0; kt < nk; ++kt) {
    const int buf = kt & 1;
    __syncthreads();
    if (kt + 1 < nk) stage(kt + 1, buf ^ 1);
    for (int kk = 0; kk < 2; ++kk) {
      const int kg = (kk << 2) + lq;
      const int sw = (kg ^ (lr & 7)) << 3;
      bf16x8 af[2], bf[4];
      for (int i = 0; i < 2; ++i)
        af[i] = *(const bf16x8*)&As[buf][(m0 + (i << 4) + lr) * 64 + sw];
      for (int j = 0; j < 4; ++j)
        bf[j] = *(const bf16x8*)&Bs[buf][(n0 + (j << 4) + lr) * 64 + sw];
      for (int i = 0; i < 2; ++i)
        for (int j = 0; j < 4; ++j)
          acc[i][j] = __builtin_amdgcn_mfma_f32_16x16x32_bf16(af[i], bf[j], acc[i][j], 0, 0, 0);
    }
  }

  for (int i = 0; i < 2; ++i) {
    for (int j = 0; j < 4; ++j) {
      const int cg = nb + n0 + (j << 4) + lr;
      for (int r = 0; r < 4; ++r) {
        const int rg = mb + m0 + (i << 4) + (lq << 2) + r;
        float v = acc[i][j][r];
        if (EPI == 1) {
          v += st_in[(size_t)rg * st_ld + cg];
          v = v > 0.f ? v : 0.f;
          outf[(size_t)rg * outf_ld + cg] = v;
          outb[(size_t)rg * outb_ld + cg] = f2bf(v);
        } else if (EPI == 2) {
          if (cg < nvalid)
            outf[(size_t)rg * outf_ld + cg] = v + bias[cg];
        } else {
          v += bias[cg];
          v = v > 0.f ? v : 0.f;
          outb[(size_t)rg * outb_ld + cg] = f2bf(v);
        }
      }
    }
  }
}

// ---------------------------------------------------------------------------
// R11 experiment: recurrent GEMM with A fragments loaded DIRECT from global
// (registers), B via LDS DMA. Rationale: R10 arithmetic shows the rec GEMM
// time = serialized sum of LDS-issue (576 cyc/block-iter) + MFMA (310) +
// VMEM (~200); A-direct cuts LDS issue by 1/3 (12 -> 8 b128/wave-iter) and
// removes A staging. A (state bf16, 8 MB) is L2/L3-resident; fragment loads
// coalesce into 64B row-segments. Software-pipelined: anext loaded during
// compute of kt. Fixed geometry: lda=ldb=st_ld=out_ld=4096, K=4096, EPI 1.
// ---------------------------------------------------------------------------
__global__ __launch_bounds__(256)
void gemm_ad(const u16* __restrict__ A, const u16* __restrict__ Bt,
             const float* __restrict__ st_in,
             float* __restrict__ outf, u16* __restrict__ outb) {
  __shared__ __align__(16) u16 Bs[2][128 * 64];
  const int t = threadIdx.x;
  const int w = t >> 6, lane = t & 63;
  const int mb = blockIdx.y << 6, nb = blockIdx.x << 7;
  const int m0 = (w & 1) << 5, n0 = (w >> 1) << 6;
  const int lr = lane & 15, lq = lane >> 4;

  f32x4 acc[2][4] = {};
  const int nk = 64;

  auto stageB = [&](int kt, int buf) {
    const int kb = kt << 6;
    for (int i = 0; i < 4; ++i) {
      const int c   = (w << 8) + (i << 6) + lane;
      const int row = c >> 3;
      const int kg  = (c & 7) ^ (row & 7);
      gl_lds16(Bt + (size_t)(nb + row) * 4096 + kb + (kg << 3),
               (char*)Bs[buf] + c * 16);
    }
  };
  const u16* arow[2];
  for (int i = 0; i < 2; ++i)
    arow[i] = A + (size_t)(mb + m0 + (i << 4) + lr) * 4096;

  bf16x8 areg[2][2], anext[2][2];
  auto loadA = [&](int kt, bf16x8 a[2][2]) {
    const int kb = kt << 6;
    for (int i = 0; i < 2; ++i)
      for (int kk = 0; kk < 2; ++kk)
        a[i][kk] = *(const bf16x8*)&arow[i][kb + (((kk << 2) + lq) << 3)];
  };

  loadA(0, areg);
  stageB(0, 0);
  for (int kt = 0; kt < nk; ++kt) {
    const int buf = kt & 1;
    __syncthreads();                       // B tile kt visible
    if (kt + 1 < nk) { stageB(kt + 1, buf ^ 1); loadA(kt + 1, anext); }
    for (int kk = 0; kk < 2; ++kk) {
      const int kg = (kk << 2) + lq;
      const int sw = (kg ^ (lr & 7)) << 3;
      bf16x8 bf[4];
      for (int j = 0; j < 4; ++j)
        bf[j] = *(const bf16x8*)&Bs[buf][(n0 + (j << 4) + lr) * 64 + sw];
      for (int i = 0; i < 2; ++i)
        for (int j = 0; j < 4; ++j)
          acc[i][j] = __builtin_amdgcn_mfma_f32_16x16x32_bf16(areg[i][kk], bf[j], acc[i][j], 0, 0, 0);
    }
    for (int i = 0; i < 2; ++i)
      for (int kk = 0; kk < 2; ++kk) areg[i][kk] = anext[i][kk];
  }

  for (int i = 0; i < 2; ++i) {
    for (int j = 0; j < 4; ++j) {
      const int cg = nb + n0 + (j << 4) + lr;
      for (int r = 0; r < 4; ++r) {
        const int rg = mb + m0 + (i << 4) + (lq << 2) + r;
        float v = acc[i][j][r] + st_in[(size_t)rg * 4096 + cg];
        v = v > 0.f ? v : 0.f;
        outf[(size_t)rg * 4096 + cg] = v;
        outb[(size_t)rg * 4096 + cg] = f2bf(v);
      }
    }
  }
}

// ---------------------------------------------------------------------------
// E-stage GEMM, split-K=4 (R11: was 2; 512 blocks = 2 blocks/CU).
// z chunks: 13,13,13,12 K-iters from k0 = z*832.
// ---------------------------------------------------------------------------
__global__ __launch_bounds__(256)
void gemm_e(const u16* __restrict__ A, const u16* __restrict__ Bt,
            float* __restrict__ part) {
  __shared__ __align__(16) u16 As[2][64 * 64];
  __shared__ __align__(16) u16 Bs[2][128 * 64];
  const int t = threadIdx.x;
  const int w = t >> 6, lane = t & 63;
  const int mb = blockIdx.y << 6, nb = blockIdx.x << 7;
  const int m0 = (w & 1) << 5, n0 = (w >> 1) << 6;
  const int lr = lane & 15, lq = lane >> 4;
  const int z = blockIdx.z;
  const int k0 = z * 832;
  const int nk = (z == 3) ? 12 : 13;

  f32x4 acc[2][4] = {};

  auto stage = [&](int kt, int buf) {
    const int kb = k0 + (kt << 6);
    for (int i = 0; i < 2; ++i) {
      const int c   = (w << 7) + (i << 6) + lane;
      const int row = c >> 3;
      const int kg  = (c & 7) ^ (row & 7);
      gl_lds16(A + (size_t)(mb + row) * 3328 + kb + (kg << 3),
               (char*)As[buf] + c * 16);
    }
    for (int i = 0; i < 4; ++i) {
      const int c   = (w << 8) + (i << 6) + lane;
      const int row = c >> 3;
      const int kg  = (c & 7) ^ (row & 7);
      gl_lds16(Bt + (size_t)(nb + row) * 3264 + kb + (kg << 3),
               (char*)Bs[buf] + c * 16);
    }
  };

  stage(0, 0);
  for (int kt = 0; kt < nk; ++kt) {
    const int buf = kt & 1;
    __syncthreads();
    if (kt + 1 < nk) stage(kt + 1, buf ^ 1);
    for (int kk = 0; kk < 2; ++kk) {
      const int kg = (kk << 2) + lq;
      const int sw = (kg ^ (lr & 7)) << 3;
      bf16x8 af[2], bf[4];
      for (int i = 0; i < 2; ++i)
        af[i] = *(const bf16x8*)&As[buf][(m0 + (i << 4) + lr) * 64 + sw];
      for (int j = 0; j < 4; ++j)
        bf[j] = *(const bf16x8*)&Bs[buf][(n0 + (j << 4) + lr) * 64 + sw];
      for (int i = 0; i < 2; ++i)
        for (int j = 0; j < 4; ++j)
          acc[i][j] = __builtin_amdgcn_mfma_f32_16x16x32_bf16(af[i], bf[j], acc[i][j], 0, 0, 0);
    }
  }

  float* dst = part + (size_t)z * 1024 * 1024;
  for (int i = 0; i < 2; ++i)
    for (int j = 0; j < 4; ++j) {
      const int cg = nb + n0 + (j << 4) + lr;
      for (int r = 0; r < 4; ++r) {
        const int rg = mb + m0 + (i << 4) + (lq << 2) + r;
        dst[(size_t)rg * 1024 + cg] = acc[i][j][r];
      }
    }
}

// ---------------------------------------------------------------------------
// E combine: cols < 1024: relu(p0+p1+p2+p3+bias) dual-store; cols >= 1024:
// zero-fill. grid 4096 blocks, float4/thread.
// ---------------------------------------------------------------------------
__global__ __launch_bounds__(256)
void e_combine(const float* __restrict__ part, const float* __restrict__ bias,
               float* __restrict__ st_f, u16* __restrict__ st_b) {
  const int i = (blockIdx.x * 256 + threadIdx.x) << 2;
  const int row = i >> 12, col = i & 4095;
  if (col < 1024) {
    const int pi = (row << 10) + col;
    const float4 a = *(const float4*)&part[pi];
    const float4 b = *(const float4*)&part[1024 * 1024 + pi];
    const float4 c = *(const float4*)&part[2 * 1024 * 1024 + pi];
    const float4 d = *(const float4*)&part[3 * 1024 * 1024 + pi];
    const float4 bs = *(const float4*)&bias[col];
    float v[4] = {a.x + b.x + c.x + d.x + bs.x, a.y + b.y + c.y + d.y + bs.y,
                  a.z + b.z + c.z + d.z + bs.z, a.w + b.w + c.w + d.w + bs.w};
    u16 o[4];
    for (int r = 0; r < 4; ++r) {
      v[r] = v[r] > 0.f ? v[r] : 0.f;
      o[r] = f2bf(v[r]);
    }
    *(float4*)&st_f[i] = make_float4(v[0], v[1], v[2], v[3]);
    *(ushort4*)&st_b[i] = make_ushort4(o[0], o[1], o[2], o[3]);
  } else {
    *(float4*)&st_f[i] = make_float4(0.f, 0.f, 0.f, 0.f);
    *(ushort4*)&st_b[i] = make_ushort4(0, 0, 0, 0);
  }
}

// ---------------------------------------------------------------------------
extern "C" void kernel_launch(void* const* d_in, const int* in_sizes, int n_in,
                              void* d_out, int out_size, void* d_ws, size_t ws_size,
                              hipStream_t stream) {
  const float* x     = (const float*)d_in[0];
  const float* cw[8];
  for (int i = 0; i < 8; ++i) cw[i] = (const float*)d_in[1 + i];
  const float* convb = (const float*)d_in[9];
  const float* W     = (const float*)d_in[10];
  const float* lA    = (const float*)d_in[11];
  const float* lB    = (const float*)d_in[12];
  const float* ip_w  = (const float*)d_in[13];
  const float* ip_b  = (const float*)d_in[14];
  const float* out_w = (const float*)d_in[15];
  const float* out_b = (const float*)d_in[16];
  float* out = (float*)d_out;

  char* p = (char*)d_ws;
  u16* feat   = (u16*)p;  p += (size_t)1024 * 3328 * 2;   // lda 3328 (N padded)
  u16* ip_wt  = (u16*)p;  p += (size_t)1024 * 3264 * 2;
  u16* out_wt = (u16*)p;  p += (size_t)2048 * 1024 * 2;
  u16* Wt     = (u16*)p;  p += (size_t)4096 * 4096 * 2;
  float* st_f[2];
  st_f[0] = (float*)p;    p += (size_t)1024 * 4096 * 4;
  st_f[1] = (float*)p;    p += (size_t)1024 * 4096 * 4;
  u16* st_b[2];
  st_b[0] = (u16*)p;      p += (size_t)1024 * 4096 * 2;
  st_b[1] = (u16*)p;      p += (size_t)1024 * 4096 * 2;

  // Prep buffers alias the FRONT of st_f[1]; Epart reuses the whole st_f[1]
  // (16 MB = 4 x 4 MB partials) after the prep consumers finish (weff2 +
  // conv GEMM precede gemm_e; ts=1 writes st_f[1] only after e_combine).
  char* q = (char*)st_f[1];
  u16* Xb       = (u16*)q;  q += (size_t)1024 * 512 * 2;
  u16* Wct      = (u16*)q;  q += (size_t)3328 * 512 * 2;
  float* bias_c = (float*)q; q += (size_t)3328 * 4;
  u16* lBt      = (u16*)q;  q += (size_t)4096 * 64 * 2;
  u16* lAb      = (u16*)q;  q += (size_t)4096 * 64 * 2;
  float* Epart  = (float*)st_f[1];

  // 1. fused prep: converts + transposes + conv weight scatter
  prep_all<<<5488, 256, 0, stream>>>(x, Xb, lA, lAb, ip_w, ip_wt,
                                     out_w, out_wt, lB, lBt,
                                     cw[0], cw[1], cw[2], cw[3],
                                     cw[4], cw[5], cw[6], cw[7], convb,
                                     Wct, bias_c);

  // 2. W_eff
  weff2<<<dim3(64, 64), 256, 0, stream>>>(W, lBt, lAb, Wt);

  // 3. conv as MFMA GEMM
  gemm128<3><<<dim3(26, 16), 256, 0, stream>>>(Xb, 512, Wct, 512, 512,
      bias_c, nullptr, 0, nullptr, 0, feat, 3328, 3328);

  // 4-5. t=0: state = relu(E_pad), split-K=4 E + full-width combine
  gemm_e<<<dim3(8, 16, 4), 256, 0, stream>>>(feat, ip_wt, Epart);
  e_combine<<<4096, 256, 0, stream>>>(Epart, ip_b, st_f[0], st_b[0]);

  // 6-9. t=1..4: state = relu(state + state @ W_eff); A/B:
  // ts=1,2 -> gemm_ad (A-direct, less LDS issue); ts=3,4 -> gemm128<1>
  for (int ts = 1; ts <= 4; ++ts) {
    const int cur = (ts - 1) & 1, nxt = ts & 1;
    if (ts <= 2) {
      gemm_ad<<<dim3(32, 16), 256, 0, stream>>>(st_b[cur], Wt,
          st_f[cur], st_f[nxt], st_b[nxt]);
    } else {
      gemm128<1><<<dim3(32, 16), 256, 0, stream>>>(st_b[cur], 4096, Wt, 4096, 4096,
          nullptr, st_f[cur], 4096, st_f[nxt], 4096, st_b[nxt], 4096, 4096);
    }
  }

  // 10. output: state[:, 3072:] @ out_w + out_b
  gemm128<2><<<dim3(16, 16), 256, 0, stream>>>(st_b[0] + 3072, 4096, out_wt, 1024, 1024,
      out_b, nullptr, 0, out, 1968, nullptr, 0, 1968);
}

// Round 12
// 394.742 us; speedup vs baseline: 1.2461x; 1.2461x over previous
//
#include <hip/hip_runtime.h>
#include <stdint.h>

typedef unsigned short u16;
typedef __attribute__((ext_vector_type(8))) short bf16x8;
typedef __attribute__((ext_vector_type(4))) float f32x4;

__device__ __forceinline__ u16 f2bf(float f) {
  union { float f; uint32_t u; } v; v.f = f;
  uint32_t u = v.u;
  return (u16)((u + 0x7fffu + ((u >> 16) & 1u)) >> 16);
}

__device__ __forceinline__ void gl_lds16(const void* g, void* l) {
  __builtin_amdgcn_global_load_lds(
      (const __attribute__((address_space(1))) uint32_t*)g,
      (__attribute__((address_space(3))) uint32_t*)l, 16, 0, 0);
}

__constant__ int c_off[9] = {0, 1024, 1808, 2384, 2784, 3040, 3184, 3248, 3264};

// ---------------------------------------------------------------------------
// Fused prep kernel (R11): converts + transposes + conv weight scatter.
//   [0,512)      x -> Xb bf16          [512,768)    lA -> lAb bf16
//   [768,1584)   ip_w -> ip_wt         [1584,2096)  out_w -> out_wt (pad 0)
//   [2096,2160)  lB -> lBt             [2160,5488)  Wct row scatter (o=b-2160)
// ---------------------------------------------------------------------------
__global__ __launch_bounds__(256)
void prep_all(const float* __restrict__ x, u16* __restrict__ Xb,
              const float* __restrict__ lA, u16* __restrict__ lAb,
              const float* __restrict__ ip_w, u16* __restrict__ ip_wt,
              const float* __restrict__ out_w, u16* __restrict__ out_wt,
              const float* __restrict__ lB, u16* __restrict__ lBt,
              const float* w1, const float* w2, const float* w3, const float* w4,
              const float* w5, const float* w6, const float* w7, const float* w8,
              const float* __restrict__ cb,
              u16* __restrict__ Wct, float* __restrict__ bias_c) {
  __shared__ float tile[64][65];
  int b = blockIdx.x;
  const int t = threadIdx.x;
  if (b < 512) {
    const int i = b * 256 + t;
    const float4 v = ((const float4*)x)[i];
    ((ushort4*)Xb)[i] = make_ushort4(f2bf(v.x), f2bf(v.y), f2bf(v.z), f2bf(v.w));
    return;
  }
  b -= 512;
  if (b < 256) {
    const int i = b * 256 + t;
    const float4 v = ((const float4*)lA)[i];
    ((ushort4*)lAb)[i] = make_ushort4(f2bf(v.x), f2bf(v.y), f2bf(v.z), f2bf(v.w));
    return;
  }
  b -= 256;
  if (b < 1392) {
    const float* src; u16* dst; int R, C, bx, by;
    if (b < 816)        { src = ip_w;  dst = ip_wt;  R = 3264; C = 1024; bx = b % 16; by = b / 16; }
    else if (b < 1328)  { b -= 816;  src = out_w; dst = out_wt; R = 1024; C = 1968; bx = b % 32; by = b / 32; }
    else                { b -= 1328; src = lB;    dst = lBt;    R = 64;   C = 4096; bx = b;      by = 0; }
    const int rb = by << 6, cbs = bx << 6;
    for (int i = 0; i < 16; ++i) {
      const int idx = t + (i << 8);
      const int r = idx >> 6, c = idx & 63;
      float v = 0.f;
      if (cbs + c < C) v = src[(size_t)(rb + r) * C + cbs + c];
      tile[r][c] = v;
    }
    __syncthreads();
    for (int i = 0; i < 16; ++i) {
      const int idx = t + (i << 8);
      const int c = idx >> 6, r = idx & 63;
      dst[(size_t)(cbs + c) * R + rb + r] = f2bf(tile[r][c]);
    }
    return;
  }
  const int o = b - 1392;
  u16* row = Wct + (size_t)o * 512;
  if (t < 128) *(ushort4*)(row + (t << 2)) = make_ushort4(0, 0, 0, 0);
  if (o >= 3264) {
    if (t == 0) bias_c[o] = 0.f;
    return;
  }
  __syncthreads();
  const float* ws[8] = {w1, w2, w3, w4, w5, w6, w7, w8};
  int kidx = 0;
  while (o >= c_off[kidx + 1]) ++kidx;
  const int ks = kidx + 1;
  const int s  = 8 - kidx;
  const int r  = o - c_off[kidx];
  const int f   = r / (s * s);
  const int rem = r - f * s * s;
  const int oi  = rem / s;
  const int oj  = rem - oi * s;
  const float* w = ws[kidx] + (size_t)f * 8 * ks * ks;
  const int ne = 8 * ks * ks;
  for (int e = t; e < ne; e += 256) {
    const int c  = e / (ks * ks);
    const int er = e - c * ks * ks;
    const int di = er / ks;
    const int dj = er - di * ks;
    row[((oi + di) * 8 + (oj + dj)) * 8 + c] = f2bf(w[(c * ks + di) * ks + dj]);
  }
  if (t == 0) bias_c[o] = cb[kidx * 16 + f];
}

// ---------------------------------------------------------------------------
// W_eff kernel (R8 win, ~18us).
// ---------------------------------------------------------------------------
__global__ __launch_bounds__(256)
void weff2(const float* __restrict__ W, const u16* __restrict__ lBt,
           const u16* __restrict__ lAb, u16* __restrict__ Wt) {
  __shared__ __align__(16) u16 As_[64 * 64];
  __shared__ __align__(16) u16 Bs_[64 * 64];
  __shared__ __align__(16) float Wl[64 * 64];
  __shared__ u16 Ct[64 * 68];
  const int t = threadIdx.x;
  const int w = t >> 6, lane = t & 63;
  const int nb = blockIdx.x << 6, kb = blockIdx.y << 6;
  const int m0 = (w & 1) << 5, n0 = (w >> 1) << 5;
  const int lr = lane & 15, lq = lane >> 4;

  for (int i = 0; i < 2; ++i) {
    const int c   = (w << 7) + (i << 6) + lane;
    const int row = c >> 3;
    const int kg  = (c & 7) ^ (row & 7);
    gl_lds16(lBt + (size_t)(nb + row) * 64 + (kg << 3), (char*)As_ + c * 16);
    gl_lds16(lAb + (size_t)(kb + row) * 64 + (kg << 3), (char*)Bs_ + c * 16);
  }
  for (int i = 0; i < 4; ++i) {
    const int c   = (w << 8) + (i << 6) + lane;
    const int row = c >> 4;
    const int cc  = (c & 15) ^ (row & 15);
    gl_lds16(W + (size_t)(kb + row) * 4096 + nb + (cc << 2), (char*)Wl + c * 16);
  }
  __syncthreads();

  f32x4 acc[2][2] = {};
  for (int kk = 0; kk < 2; ++kk) {
    const int kg = (kk << 2) + lq;
    const int sw = (kg ^ (lr & 7)) << 3;
    bf16x8 af[2], bf[2];
    for (int i = 0; i < 2; ++i)
      af[i] = *(const bf16x8*)&As_[(m0 + (i << 4) + lr) * 64 + sw];
    for (int j = 0; j < 2; ++j)
      bf[j] = *(const bf16x8*)&Bs_[(n0 + (j << 4) + lr) * 64 + sw];
    for (int i = 0; i < 2; ++i)
      for (int j = 0; j < 2; ++j)
        acc[i][j] = __builtin_amdgcn_mfma_f32_16x16x32_bf16(af[i], bf[j], acc[i][j], 0, 0, 0);
  }

  for (int i = 0; i < 2; ++i) {
    for (int j = 0; j < 2; ++j) {
      const int cg  = n0 + (j << 4) + lr;
      const int rg0 = m0 + (i << 4) + (lq << 2);
      const int ch  = (rg0 >> 2) ^ (cg & 15);
      const float4 wv4 = *(const float4*)&Wl[cg * 64 + (ch << 2)];
      const float wv[4] = {wv4.x, wv4.y, wv4.z, wv4.w};
      for (int r = 0; r < 4; ++r)
        Ct[(rg0 + r) * 68 + cg] =
            (wv[r] != 0.f) ? f2bf(wv[r] + 2.0f * acc[i][j][r]) : (u16)0;
    }
  }
  __syncthreads();

  const int row = t >> 2, kp = (t & 3) << 4;
  u16* dst = Wt + (size_t)(nb + row) * 4096 + kb + kp;
  const u16* src = &Ct[row * 68 + kp];
  for (int i = 0; i < 4; ++i)
    *(ushort4*)(dst + (i << 2)) = *(const ushort4*)(src + (i << 2));
}

// ---------------------------------------------------------------------------
// bf16 MFMA GEMM, 64x128 block tile, 4 waves (32x64), BK=64, dbuf LDS,
// XOR-swizzled. The workhorse (~570 TF). Six structural alternatives lost
// to this (R5-R11) — the rec inner loop is settled.
// EPI 1: relu(acc + st_in) -> outf + outb   [recurrent]
// EPI 2: acc + bias -> outf, n < nvalid     [output]
// EPI 3: relu(acc + bias) -> outb only      [conv feat]
// ---------------------------------------------------------------------------
template<int EPI>
__global__ __launch_bounds__(256)
void gemm128(const u16* __restrict__ A, int lda,
             const u16* __restrict__ Bt, int ldb, int K,
             const float* __restrict__ bias,
             const float* __restrict__ st_in, int st_ld,
             float* __restrict__ outf, int outf_ld,
             u16* __restrict__ outb, int outb_ld, int nvalid) {
  __shared__ __align__(16) u16 As[2][64 * 64];
  __shared__ __align__(16) u16 Bs[2][128 * 64];
  const int t = threadIdx.x;
  const int w = t >> 6, lane = t & 63;
  const int mb = blockIdx.y << 6, nb = blockIdx.x << 7;
  const int m0 = (w & 1) << 5, n0 = (w >> 1) << 6;
  const int lr = lane & 15, lq = lane >> 4;

  f32x4 acc[2][4] = {};
  const int nk = K >> 6;

  auto stage = [&](int kt, int buf) {
    const int kb = kt << 6;
    for (int i = 0; i < 2; ++i) {
      const int c   = (w << 7) + (i << 6) + lane;
      const int row = c >> 3;
      const int kg  = (c & 7) ^ (row & 7);
      gl_lds16(A + (size_t)(mb + row) * lda + kb + (kg << 3),
               (char*)As[buf] + c * 16);
    }
    for (int i = 0; i < 4; ++i) {
      const int c   = (w << 8) + (i << 6) + lane;
      const int row = c >> 3;
      const int kg  = (c & 7) ^ (row & 7);
      gl_lds16(Bt + (size_t)(nb + row) * ldb + kb + (kg << 3),
               (char*)Bs[buf] + c * 16);
    }
  };

  stage(0, 0);
  for (int kt = 0; kt < nk; ++kt) {
    const int buf = kt & 1;
    __syncthreads();
    if (kt + 1 < nk) stage(kt + 1, buf ^ 1);
    for (int kk = 0; kk < 2; ++kk) {
      const int kg = (kk << 2) + lq;
      const int sw = (kg ^ (lr & 7)) << 3;
      bf16x8 af[2], bf[4];
      for (int i = 0; i < 2; ++i)
        af[i] = *(const bf16x8*)&As[buf][(m0 + (i << 4) + lr) * 64 + sw];
      for (int j = 0; j < 4; ++j)
        bf[j] = *(const bf16x8*)&Bs[buf][(n0 + (j << 4) + lr) * 64 + sw];
      for (int i = 0; i < 2; ++i)
        for (int j = 0; j < 4; ++j)
          acc[i][j] = __builtin_amdgcn_mfma_f32_16x16x32_bf16(af[i], bf[j], acc[i][j], 0, 0, 0);
    }
  }

  for (int i = 0; i < 2; ++i) {
    for (int j = 0; j < 4; ++j) {
      const int cg = nb + n0 + (j << 4) + lr;
      for (int r = 0; r < 4; ++r) {
        const int rg = mb + m0 + (i << 4) + (lq << 2) + r;
        float v = acc[i][j][r];
        if (EPI == 1) {
          v += st_in[(size_t)rg * st_ld + cg];
          v = v > 0.f ? v : 0.f;
          outf[(size_t)rg * outf_ld + cg] = v;
          outb[(size_t)rg * outb_ld + cg] = f2bf(v);
        } else if (EPI == 2) {
          if (cg < nvalid)
            outf[(size_t)rg * outf_ld + cg] = v + bias[cg];
        } else {
          v += bias[cg];
          v = v > 0.f ? v : 0.f;
          outb[(size_t)rg * outb_ld + cg] = f2bf(v);
        }
      }
    }
  }
}

// ---------------------------------------------------------------------------
// E-stage GEMM, split-K=4. z chunks: 13,13,13,12 K-iters from k0 = z*832.
// ---------------------------------------------------------------------------
__global__ __launch_bounds__(256)
void gemm_e(const u16* __restrict__ A, const u16* __restrict__ Bt,
            float* __restrict__ part) {
  __shared__ __align__(16) u16 As[2][64 * 64];
  __shared__ __align__(16) u16 Bs[2][128 * 64];
  const int t = threadIdx.x;
  const int w = t >> 6, lane = t & 63;
  const int mb = blockIdx.y << 6, nb = blockIdx.x << 7;
  const int m0 = (w & 1) << 5, n0 = (w >> 1) << 6;
  const int lr = lane & 15, lq = lane >> 4;
  const int z = blockIdx.z;
  const int k0 = z * 832;
  const int nk = (z == 3) ? 12 : 13;

  f32x4 acc[2][4] = {};

  auto stage = [&](int kt, int buf) {
    const int kb = k0 + (kt << 6);
    for (int i = 0; i < 2; ++i) {
      const int c   = (w << 7) + (i << 6) + lane;
      const int row = c >> 3;
      const int kg  = (c & 7) ^ (row & 7);
      gl_lds16(A + (size_t)(mb + row) * 3328 + kb + (kg << 3),
               (char*)As[buf] + c * 16);
    }
    for (int i = 0; i < 4; ++i) {
      const int c   = (w << 8) + (i << 6) + lane;
      const int row = c >> 3;
      const int kg  = (c & 7) ^ (row & 7);
      gl_lds16(Bt + (size_t)(nb + row) * 3264 + kb + (kg << 3),
               (char*)Bs[buf] + c * 16);
    }
  };

  stage(0, 0);
  for (int kt = 0; kt < nk; ++kt) {
    const int buf = kt & 1;
    __syncthreads();
    if (kt + 1 < nk) stage(kt + 1, buf ^ 1);
    for (int kk = 0; kk < 2; ++kk) {
      const int kg = (kk << 2) + lq;
      const int sw = (kg ^ (lr & 7)) << 3;
      bf16x8 af[2], bf[4];
      for (int i = 0; i < 2; ++i)
        af[i] = *(const bf16x8*)&As[buf][(m0 + (i << 4) + lr) * 64 + sw];
      for (int j = 0; j < 4; ++j)
        bf[j] = *(const bf16x8*)&Bs[buf][(n0 + (j << 4) + lr) * 64 + sw];
      for (int i = 0; i < 2; ++i)
        for (int j = 0; j < 4; ++j)
          acc[i][j] = __builtin_amdgcn_mfma_f32_16x16x32_bf16(af[i], bf[j], acc[i][j], 0, 0, 0);
    }
  }

  float* dst = part + (size_t)z * 1024 * 1024;
  for (int i = 0; i < 2; ++i)
    for (int j = 0; j < 4; ++j) {
      const int cg = nb + n0 + (j << 4) + lr;
      for (int r = 0; r < 4; ++r) {
        const int rg = mb + m0 + (i << 4) + (lq << 2) + r;
        dst[(size_t)rg * 1024 + cg] = acc[i][j][r];
      }
    }
}

// ---------------------------------------------------------------------------
// E combine: cols < 1024: relu(p0+p1+p2+p3+bias) dual-store; cols >= 1024:
// zero-fill.
// ---------------------------------------------------------------------------
__global__ __launch_bounds__(256)
void e_combine(const float* __restrict__ part, const float* __restrict__ bias,
               float* __restrict__ st_f, u16* __restrict__ st_b) {
  const int i = (blockIdx.x * 256 + threadIdx.x) << 2;
  const int row = i >> 12, col = i & 4095;
  if (col < 1024) {
    const int pi = (row << 10) + col;
    const float4 a = *(const float4*)&part[pi];
    const float4 b = *(const float4*)&part[1024 * 1024 + pi];
    const float4 c = *(const float4*)&part[2 * 1024 * 1024 + pi];
    const float4 d = *(const float4*)&part[3 * 1024 * 1024 + pi];
    const float4 bs = *(const float4*)&bias[col];
    float v[4] = {a.x + b.x + c.x + d.x + bs.x, a.y + b.y + c.y + d.y + bs.y,
                  a.z + b.z + c.z + d.z + bs.z, a.w + b.w + c.w + d.w + bs.w};
    u16 o[4];
    for (int r = 0; r < 4; ++r) {
      v[r] = v[r] > 0.f ? v[r] : 0.f;
      o[r] = f2bf(v[r]);
    }
    *(float4*)&st_f[i] = make_float4(v[0], v[1], v[2], v[3]);
    *(ushort4*)&st_b[i] = make_ushort4(o[0], o[1], o[2], o[3]);
  } else {
    *(float4*)&st_f[i] = make_float4(0.f, 0.f, 0.f, 0.f);
    *(ushort4*)&st_b[i] = make_ushort4(0, 0, 0, 0);
  }
}

// ---------------------------------------------------------------------------
extern "C" void kernel_launch(void* const* d_in, const int* in_sizes, int n_in,
                              void* d_out, int out_size, void* d_ws, size_t ws_size,
                              hipStream_t stream) {
  const float* x     = (const float*)d_in[0];
  const float* cw[8];
  for (int i = 0; i < 8; ++i) cw[i] = (const float*)d_in[1 + i];
  const float* convb = (const float*)d_in[9];
  const float* W     = (const float*)d_in[10];
  const float* lA    = (const float*)d_in[11];
  const float* lB    = (const float*)d_in[12];
  const float* ip_w  = (const float*)d_in[13];
  const float* ip_b  = (const float*)d_in[14];
  const float* out_w = (const float*)d_in[15];
  const float* out_b = (const float*)d_in[16];
  float* out = (float*)d_out;

  char* p = (char*)d_ws;
  u16* feat   = (u16*)p;  p += (size_t)1024 * 3328 * 2;
  u16* ip_wt  = (u16*)p;  p += (size_t)1024 * 3264 * 2;
  u16* out_wt = (u16*)p;  p += (size_t)2048 * 1024 * 2;
  u16* Wt     = (u16*)p;  p += (size_t)4096 * 4096 * 2;
  float* st_f[2];
  st_f[0] = (float*)p;    p += (size_t)1024 * 4096 * 4;
  st_f[1] = (float*)p;    p += (size_t)1024 * 4096 * 4;
  u16* st_b[2];
  st_b[0] = (u16*)p;      p += (size_t)1024 * 4096 * 2;
  st_b[1] = (u16*)p;      p += (size_t)1024 * 4096 * 2;

  // Prep buffers alias the front of st_f[1]; Epart reuses all of st_f[1]
  // (16 MB = 4 x 4 MB partials); ts=1 writes st_f[1] only after e_combine.
  char* q = (char*)st_f[1];
  u16* Xb       = (u16*)q;  q += (size_t)1024 * 512 * 2;
  u16* Wct      = (u16*)q;  q += (size_t)3328 * 512 * 2;
  float* bias_c = (float*)q; q += (size_t)3328 * 4;
  u16* lBt      = (u16*)q;  q += (size_t)4096 * 64 * 2;
  u16* lAb      = (u16*)q;  q += (size_t)4096 * 64 * 2;
  float* Epart  = (float*)st_f[1];

  // 1. fused prep
  prep_all<<<5488, 256, 0, stream>>>(x, Xb, lA, lAb, ip_w, ip_wt,
                                     out_w, out_wt, lB, lBt,
                                     cw[0], cw[1], cw[2], cw[3],
                                     cw[4], cw[5], cw[6], cw[7], convb,
                                     Wct, bias_c);

  // 2. W_eff
  weff2<<<dim3(64, 64), 256, 0, stream>>>(W, lBt, lAb, Wt);

  // 3. conv as MFMA GEMM
  gemm128<3><<<dim3(26, 16), 256, 0, stream>>>(Xb, 512, Wct, 512, 512,
      bias_c, nullptr, 0, nullptr, 0, feat, 3328, 3328);

  // 4-5. t=0: state = relu(E_pad), split-K=4 E + combine (zeros cols >= 1024)
  gemm_e<<<dim3(8, 16, 4), 256, 0, stream>>>(feat, ip_wt, Epart);
  e_combine<<<4096, 256, 0, stream>>>(Epart, ip_b, st_f[0], st_b[0]);

  // 6. t=1: state cols >= 1024 are EXACTLY zero (E_pad zero-fill + relu),
  //    so state @ W_eff needs only K=1024 — bit-identical, 4x less work.
  gemm128<1><<<dim3(32, 16), 256, 0, stream>>>(st_b[0], 4096, Wt, 4096, 1024,
      nullptr, st_f[0], 4096, st_f[1], 4096, st_b[1], 4096, 4096);

  // 7-8. t=2,3: full K=4096, N=4096
  gemm128<1><<<dim3(32, 16), 256, 0, stream>>>(st_b[1], 4096, Wt, 4096, 4096,
      nullptr, st_f[1], 4096, st_f[0], 4096, st_b[0], 4096, 4096);
  gemm128<1><<<dim3(32, 16), 256, 0, stream>>>(st_b[0], 4096, Wt, 4096, 4096,
      nullptr, st_f[0], 4096, st_f[1], 4096, st_b[1], 4096, 4096);

  // 9. t=4: only state cols [3072,4096) are read downstream -> N=1024:
  //    Bt rows 3072+, all output pointers offset by 3072. Bit-identical.
  gemm128<1><<<dim3(8, 16), 256, 0, stream>>>(st_b[1], 4096,
      Wt + (size_t)3072 * 4096, 4096, 4096,
      nullptr, st_f[1] + 3072, 4096, st_f[0] + 3072, 4096,
      st_b[0] + 3072, 4096, 4096);

  // 10. output: state[:, 3072:] @ out_w + out_b
  gemm128<2><<<dim3(16, 16), 256, 0, stream>>>(st_b[0] + 3072, 4096, out_wt, 1024, 1024,
      out_b, nullptr, 0, out, 1968, nullptr, 0, 1968);
}